// Round 1
// 379.449 us; speedup vs baseline: 1.1003x; 1.1003x over previous
//
#include <hip/hip_runtime.h>
#include <cstdint>
#include <math.h>

#define BATCH    65536
#define HIS_LEN  5
#define KIND_LEN 10
#define SB       128   // samples per block
#define NTH      512   // threads per block (8 waves)

typedef float v2f __attribute__((ext_vector_type(2)));
__device__ __forceinline__ v2f mk2(float a, float b){ v2f r; r.x=a; r.y=b; return r; }

// ---- ws layout (fp32 element offsets) — unchanged ----
#define OFF_WC1 0        // 12288
#define OFF_AB1 12288    // 64
#define OFF_W2T 12352    // 2048  [o*32+p]
#define OFF_AB2 14400    // 32
#define OFF_W3  14432    // 32
#define OFF_AB3 14464    // 1
#define OFF_M1  14720    // 26624 [128 o][4 q][52] sliced
#define OFF_MB1 41344    // 128
#define OFF_M2T 41472    // 8192  [o*64+p]
#define OFF_MB2 49664    // 64
#define OFF_M3T 49728    // 2048  [o*32+p]
#define OFF_MB3 51776    // 32
#define OFF_M4  51808    // 32
#define OFF_MB4 51840    // 1
#define PREP_N  51586

// LDS float layout:
//   [0,6144)      two 768-f4 chunk buffers (buf0 f4 [0,768), buf1 f4 [768,1536))
//                 history keeps BOTH weight chunks resident -> zero re-staging
//   [6144,8450)   persistent PF (AB1,W2T,AB2,W3,AB3 | MB2 | MB3,M4,MB4)
//   [8450,12546)  tp: 8192 bf16 = 64 outputs x 128 samples  (t2 + ab1, bf16)
#define PFF   6144
#define W2TF4 1552      // (PFF+64)/4
#define LDSF  12546

typedef const float* fp;

// lane q owns feature elements idx = 8r + 2q + e (r<11, e<2) of each 88-vec
__global__ void din_prep(fp aw1, fp ab1, fp aw2, fp ab2, fp aw3, fp ab3,
                         fp m1,  fp mb1, fp m2,  fp mb2, fp m3,  fp mb3,
                         fp m4,  fp mb4, float* __restrict__ ws){
  int i = blockIdx.x*blockDim.x + threadIdx.x;
  int j = i;
  if(j < 12288){ // act_w1 combined+sliced+padded
    int o = j/192, t = j%192;
    int h = t/96; int tt = t - 96*h;
    int q = tt/24, d = tt - 24*q;
    float v = 0.f;
    if(d < 22){
      int idx = 8*(d>>1) + 2*q + (d&1);
      v = (h==0) ? (aw1[o*264+idx] + aw1[o*264+88+idx])
                 : (aw1[o*264+176+idx] - aw1[o*264+88+idx]);
    }
    ws[OFF_WC1 + j] = v; return;
  } j -= 12288;
  if(j < 64){ ws[OFF_AB1 + j] = ab1[j]; return; } j -= 64;
  if(j < 2048){ int o=j/32, p=j%32; ws[OFF_W2T + j] = aw2[p*64 + o]; return; } j -= 2048;
  if(j < 32){ ws[OFF_AB2 + j] = ab2[j]; return; } j -= 32;
  if(j < 32){ ws[OFF_W3  + j] = aw3[j]; return; } j -= 32;
  if(j < 1){ ws[OFF_AB3] = ab3[0]; return; } j -= 1;
  if(j < 26624){ // mlp_w1 sliced: [ex8 | i2part22 | poolpart22] per q
    int o = j/208, r = j%208;
    int q = r/52, t = r-52*q;
    int src;
    if(t<8){ int E = (q==0)?0:(8+8*q); src = E + t; }
    else if(t<30){ int d=t-8; int idx = 8*(d>>1)+2*q+(d&1);
                   src = (idx<8) ? (8+idx) : (32+idx); }
    else { int d=t-30; int idx = 8*(d>>1)+2*q+(d&1); src = 120+idx; }
    ws[OFF_M1 + j] = m1[o*208 + src]; return;
  } j -= 26624;
  if(j < 128){ ws[OFF_MB1 + j] = mb1[j]; return; } j -= 128;
  if(j < 8192){ int o=j/64, p=j%64; ws[OFF_M2T + j] = m2[p*128 + o]; return; } j -= 8192;
  if(j < 64){ ws[OFF_MB2 + j] = mb2[j]; return; } j -= 64;
  if(j < 2048){ int o=j/32, p=j%32; ws[OFF_M3T + j] = m3[p*64 + o]; return; } j -= 2048;
  if(j < 32){ ws[OFF_MB3 + j] = mb3[j]; return; } j -= 32;
  if(j < 32){ ws[OFF_M4  + j] = m4[j];  return; } j -= 32;
  if(j < 1){ ws[OFF_MB4] = mb4[0]; return; }
}

__device__ __forceinline__ float bsum4(float v){
  v += __shfl_xor(v, 1);
  v += __shfl_xor(v, 2);
  return v;
}
__device__ __forceinline__ unsigned short f2bf(float f){
  unsigned int u = __float_as_uint(f);
  return (unsigned short)((u + 0x7fffu + ((u>>16)&1u)) >> 16);
}
__device__ __forceinline__ float bf2f(unsigned short s){
  return __uint_as_float(((unsigned int)s) << 16);
}

// async global->LDS staging (dest must be wave-uniform base + lane*size; all
// our staging indices are k*NTH+tid => lane-linear within each wave)
__device__ __forceinline__ void ldst16(void* l, const void* g){
  __builtin_amdgcn_global_load_lds(
      (const __attribute__((address_space(1))) unsigned int*)(uintptr_t)g,
      (__attribute__((address_space(3))) unsigned int*)(uintptr_t)l, 16, 0, 0);
}
__device__ __forceinline__ void ldst4(void* l, const void* g){
  __builtin_amdgcn_global_load_lds(
      (const __attribute__((address_space(1))) unsigned int*)(uintptr_t)g,
      (__attribute__((address_space(3))) unsigned int*)(uintptr_t)l, 4, 0, 0);
}

__device__ __forceinline__ void gather_slice(const float2* __restrict__ itemp,
                                             const float2* __restrict__ kindp,
                                             int item_idx, const int* __restrict__ kidx,
                                             int q, v2f* f){
  float2 v = itemp[item_idx*4 + q];
  f[0] = mk2(v.x, v.y);
  #pragma unroll
  for(int r=0;r<KIND_LEN;r++){
    int ki = kidx[r];
    float2 w = kindp[ki*4 + q];
    bool m = (ki!=0);
    f[1+r] = m ? mk2(w.x, w.y) : mk2(0.f, 0.f);
  }
}

#define PKF(acc, a, b, vv) do{ (acc) = __builtin_elementwise_fma(mk2((a),(b)), (vv), (acc)); }while(0)

// one history pass over NS steps, sharing every weight ds_read across the steps.
// Both weight chunks are resident (ls4[0..1536)), row oo at f4 oo*24.
template<int NS>
__device__ __forceinline__ void hist_pass(int b, int s0, int q, int wid,
    const float2* __restrict__ item_emb, const float2* __restrict__ kind_emb,
    const int* __restrict__ his_id, const int* __restrict__ his_kind,
    const float* ls, const float4* ls4, const unsigned short* tp, v2f* poolv){
  v2f i1v[NS][11];
  #pragma unroll
  for(int t=0;t<NS;t++)
    gather_slice(item_emb, kind_emb, his_id[b*HIS_LEN + s0 + t],
                 his_kind + (b*HIS_LEN + s0 + t)*KIND_LEN, q, i1v[t]);
  v2f h2v[NS][4];
  #pragma unroll
  for(int t=0;t<NS;t++)
    #pragma unroll
    for(int j=0;j<4;j++) h2v[t][j] = mk2(0.f,0.f);

  #pragma unroll 1
  for(int oo=0;oo<64;oo++){
    const float4* wr = ls4 + oo*24 + 6*q;
    float t2b = bf2f(tp[oo*SB + wid]);            // t2 + ab1 (bf16-cached)
    v2f aA[NS], aB[NS];
    #pragma unroll
    for(int t=0;t<NS;t++){ aA[t]=mk2(0.f,0.f); aB[t]=mk2(0.f,0.f); }
    #pragma unroll
    for(int k=0;k<5;k++){
      float4 w = wr[k];
      #pragma unroll
      for(int t=0;t<NS;t++){
        PKF(aA[t], w.x, w.y, i1v[t][2*k]);
        PKF(aB[t], w.z, w.w, i1v[t][2*k+1]);
      }
    }
    { float4 w = wr[5];
      #pragma unroll
      for(int t=0;t<NS;t++) PKF(aA[t], w.x, w.y, i1v[t][10]); }
    float4 wa = ls4[W2TF4 + oo*8 + 2*q];
    float4 wb = ls4[W2TF4 + 1 + oo*8 + 2*q];
    #pragma unroll
    for(int t=0;t<NS;t++){
      float h = bsum4((aA[t].x+aB[t].x)+(aA[t].y+aB[t].y)) + t2b;
      h = fmaxf(h, 0.f);
      v2f hh = mk2(h, h);
      PKF(h2v[t][0], wa.x, wa.y, hh);
      PKF(h2v[t][1], wa.z, wa.w, hh);
      PKF(h2v[t][2], wb.x, wb.y, hh);
      PKF(h2v[t][3], wb.z, wb.w, hh);
    }
  }
  #pragma unroll
  for(int t=0;t<NS;t++){
    float scp = 0.f;
    #pragma unroll
    for(int jj=0;jj<4;jj++){
      float hx = fmaxf(h2v[t][jj].x + ls[PFF+2112+8*q+2*jj],   0.f);
      float hy = fmaxf(h2v[t][jj].y + ls[PFF+2112+8*q+2*jj+1], 0.f);
      scp += ls[PFF+2144+8*q+2*jj]*hx + ls[PFF+2144+8*q+2*jj+1]*hy;
    }
    float sc = bsum4(scp) + ls[PFF+2176];
    v2f scv = mk2(sc, sc);
    #pragma unroll
    for(int d=0;d<11;d++){
      v2f tt = i1v[t][d]*scv;
      poolv[d] = __builtin_elementwise_fma(tt, i1v[t][d], poolv[d]);
    }
  }
}

__device__ __forceinline__ void mlp_stage(int c, int tid, float* ls, float4* ls4,
                                          const float* ws, const float4* ws4){
  int buf = (c&1)*768;
  int j = tid;   // 544 f4: M1S 416 | M2T 128
  const float4* src = (j<416) ? (ws4 + 3680 + c*416 + j)
                              : (ws4 + 10368 + c*128 + (j-416));
  ldst16(ls4 + buf + j, src);
  if(tid < 32) ldst16(ls4 + buf + 512 + tid, ws4 + 10368 + c*128 + 96 + tid);
  if(tid < 8)  ldst4(ls + buf*4 + 2176 + tid, ws + OFF_MB1 + c*8 + tid);
}

// 512 threads; 128 samples/block; quad (q=lane&3) K-splits every dot.
__global__ void __launch_bounds__(NTH, 4)
din_main(const int* __restrict__ userid, const int* __restrict__ itemid,
         const int* __restrict__ age,    const int* __restrict__ gen,
         const int* __restrict__ occ,    const int* __restrict__ item_kind,
         const int* __restrict__ his_id, const int* __restrict__ his_kind,
         const float2* __restrict__ user_emb, const float2* __restrict__ item_emb,
         const float2* __restrict__ age_emb,  const float2* __restrict__ gen_emb,
         const float2* __restrict__ occ_emb,  const float2* __restrict__ kind_emb,
         const float* __restrict__ ws, float* __restrict__ out){
  const int tid  = threadIdx.x;
  const int q    = tid & 3;
  const int sl   = (tid & 63) >> 2;
  const int wv   = __builtin_amdgcn_readfirstlane(tid >> 6);
  const int wid  = wv*16 + sl;                 // sample-in-block 0..127
  const int b    = blockIdx.x*SB + wid;

  __shared__ __align__(16) float ls[LDSF];
  float4* ls4 = (float4*)ls;
  const float* wsc = ws;
  const float4* ws4 = (const float4*)ws;
  unsigned short* tp = (unsigned short*)(ls + PFF + 2306);

  // ---- initial async staging: PF block (2306 f) + phase-A weight chunks (1536 f4) ----
  #pragma unroll
  for(int k=0;k<4;k++){ int j = k*NTH + tid; ldst4(ls + PFF + j, wsc + 12288 + j); }
  { int j = 4*NTH + tid;
    if(j < 2306){
      const float* src = (j<2177) ? (wsc + 12288 + j)
                       : (j<2241) ? (wsc + 49664 + (j-2177))
                                  : (wsc + 51776 + (j-2241));
      ldst4(ls + PFF + j, src);
    } }
  #pragma unroll
  for(int k=0;k<3;k++){
    int j = k*NTH + tid;                 // < 1536
    int r = j/24, d4 = j - r*24;
    ldst16(ls4 + j, ws4 + r*48 + 24 + d4);   // h=1 half (wC - wB)
  }

  // ---- i2 slice (overlaps staging latency) ----
  v2f i2v[11];
  gather_slice(item_emb, kind_emb, itemid[b], item_kind + b*KIND_LEN, q, i2v);

  __syncthreads();   // staging drained (barrier implies vmcnt(0))

  // ---- phase A: t2+ab1 -> bf16 tp (second-half rows vs i2) ----
  #pragma unroll 1
  for(int oo=0;oo<64;oo++){
    const float4* wr = ls4 + oo*24 + 6*q;
    v2f aA = mk2(0.f,0.f), aB = mk2(0.f,0.f);
    #pragma unroll
    for(int k=0;k<5;k++){
      float4 w = wr[k];
      PKF(aA, w.x, w.y, i2v[2*k]);
      PKF(aB, w.z, w.w, i2v[2*k+1]);
    }
    { float4 w = wr[5]; PKF(aA, w.x, w.y, i2v[10]); }
    float s = bsum4((aA.x+aB.x)+(aA.y+aB.y));
    if(q==0) tp[oo*SB + wid] = f2bf(s + ls[PFF + oo]);
  }
  __syncthreads();   // A reads + tp writes done
  #pragma unroll
  for(int k=0;k<3;k++){
    int j = k*NTH + tid;
    int r = j/24, d4 = j - r*24;
    ldst16(ls4 + j, ws4 + r*48 + d4);        // h=0 half (wA + wB), both chunks
  }
  __syncthreads();   // history weights resident for the rest of history

  // ---- history: 3 passes (2+2+1 steps), no barriers, no re-staging ----
  v2f poolv[11];
  #pragma unroll
  for(int d=0;d<11;d++) poolv[d]=mk2(0.f,0.f);
  hist_pass<2>(b, 0, q, wid, item_emb, kind_emb, his_id, his_kind, ls, ls4, tp, poolv);
  hist_pass<2>(b, 2, q, wid, item_emb, kind_emb, his_id, his_kind, ls, ls4, tp, poolv);
  hist_pass<1>(b, 4, q, wid, item_emb, kind_emb, his_id, his_kind, ls, ls4, tp, poolv);

  // ---- MLP prologue: re-gather i2 (frees regs during history), extras, h2m ----
  gather_slice(item_emb, kind_emb, itemid[b], item_kind + b*KIND_LEN, q, i2v);
  v2f exv[4];
  {
    const float2* ep = (q==0)? user_emb : (q==1)? age_emb : (q==2)? gen_emb : occ_emb;
    int ei = (q==0)? userid[b] : (q==1)? age[b] : (q==2)? gen[b] : occ[b];
    #pragma unroll
    for(int k=0;k<4;k++){ float2 v = ep[ei*4+k]; exv[k]=mk2(v.x,v.y); }
  }
  v2f h2m[8];
  #pragma unroll
  for(int j=0;j<8;j++) h2m[j] = mk2(ls[PFF+2177+16*q+2*j], ls[PFF+2177+16*q+2*j+1]);

  __syncthreads();                  // all waves done reading history bufs
  mlp_stage(0, tid, ls, ls4, wsc, ws4);
  __syncthreads();                  // chunk 0 resident

  // ---- MLP layers 1+2: 16 ping-pong chunks, 1 barrier each, async prefetch ----
  #pragma unroll 1
  for(int c=0;c<16;c++){
    int base = (c&1)*768;
    if(c<15){
      mlp_stage(c+1, tid, ls, ls4, wsc, ws4);
    } else {
      // tail: stage M3T with per-q skew (row 16q+i at f4 q*130+i*8) into buf0
      int j = tid;
      ldst16(ls4 + (j>>7)*130 + (j&127), ws4 + 12432 + j);
    }
    #pragma unroll 1
    for(int i=0;i<8;i++){
      const float4* wr = ls4 + base + i*52 + 13*q;
      v2f aA = mk2(0.f,0.f), aB = mk2(0.f,0.f);
      { float4 w = wr[0]; PKF(aA, w.x, w.y, exv[0]); PKF(aB, w.z, w.w, exv[1]); }
      { float4 w = wr[1]; PKF(aA, w.x, w.y, exv[2]); PKF(aB, w.z, w.w, exv[3]); }
      #pragma unroll
      for(int k=0;k<5;k++){
        float4 w = wr[2+k];
        PKF(aA, w.x, w.y, i2v[2*k]);
        PKF(aB, w.z, w.w, i2v[2*k+1]);
      }
      { float4 w = wr[7]; PKF(aA, w.x, w.y, i2v[10]); PKF(aB, w.z, w.w, poolv[0]); }
      #pragma unroll
      for(int k=0;k<5;k++){
        float4 w = wr[8+k];
        PKF(aA, w.x, w.y, poolv[2*k+1]);
        PKF(aB, w.z, w.w, poolv[2*k+2]);
      }
      float h = fmaxf(bsum4((aA.x+aB.x)+(aA.y+aB.y)) + ls[base*4 + 2176 + i], 0.f);
      v2f hh = mk2(h, h);
      const float4* w2 = ls4 + base + 416 + i*16 + 4*q;
      #pragma unroll
      for(int k=0;k<4;k++){
        float4 w = w2[k];
        PKF(h2m[2*k],   w.x, w.y, hh);
        PKF(h2m[2*k+1], w.z, w.w, hh);
      }
    }
    __syncthreads();   // joins waves + drains next chunk's (or tail's) loads
  }

  // ---- tail: layers 3+4 ----
  float h3p[32];
  #pragma unroll
  for(int j=0;j<32;j++) h3p[j]=0.f;
  #pragma unroll
  for(int i=0;i<16;i++){
    float hv = (i&1) ? h2m[i>>1].y : h2m[i>>1].x;
    float v = fmaxf(hv, 0.f);
    const float4* w3 = ls4 + q*130 + i*8;
    #pragma unroll
    for(int j=0;j<8;j++){
      float4 w = w3[j];
      h3p[4*j]+=w.x*v; h3p[4*j+1]+=w.y*v; h3p[4*j+2]+=w.z*v; h3p[4*j+3]+=w.w*v;
    }
  }
  #pragma unroll
  for(int j=0;j<32;j++) h3p[j] += __shfl_xor(h3p[j], 1);
  #pragma unroll
  for(int j=0;j<32;j++) h3p[j] += __shfl_xor(h3p[j], 2);

  float x = ls[PFF+2305];
  #pragma unroll
  for(int j=0;j<32;j++) x += ls[PFF+2273+j] * fmaxf(h3p[j] + ls[PFF+2241+j], 0.f);

  if(q==0) out[b] = 1.0f/(1.0f + __expf(-x));
}

extern "C" void kernel_launch(void* const* d_in, const int* in_sizes, int n_in,
                              void* d_out, int out_size, void* d_ws, size_t ws_size,
                              hipStream_t stream){
  const int* userid    = (const int*)d_in[0];
  const int* itemid    = (const int*)d_in[1];
  const int* age       = (const int*)d_in[2];
  const int* gen       = (const int*)d_in[3];
  const int* occ       = (const int*)d_in[4];
  const int* item_kind = (const int*)d_in[5];
  const int* his_id    = (const int*)d_in[6];
  const int* his_kind  = (const int*)d_in[7];
  const float2* user_emb = (const float2*)d_in[8];
  const float2* item_emb = (const float2*)d_in[9];
  const float2* age_emb  = (const float2*)d_in[10];
  const float2* gen_emb  = (const float2*)d_in[11];
  const float2* occ_emb  = (const float2*)d_in[12];
  const float2* kind_emb = (const float2*)d_in[13];
  float* ws = (float*)d_ws;

  din_prep<<<(PREP_N+255)/256, 256, 0, stream>>>(
      (fp)d_in[14], (fp)d_in[15], (fp)d_in[16], (fp)d_in[17], (fp)d_in[18], (fp)d_in[19],
      (fp)d_in[20], (fp)d_in[21], (fp)d_in[22], (fp)d_in[23], (fp)d_in[24], (fp)d_in[25],
      (fp)d_in[26], (fp)d_in[27], ws);

  din_main<<<BATCH/SB, NTH, 0, stream>>>(
      userid, itemid, age, gen, occ, item_kind, his_id, his_kind,
      user_emb, item_emb, age_emb, gen_emb, occ_emb, kind_emb,
      ws, (float*)d_out);
}